// Round 16
// baseline (361.356 us; speedup 1.0000x reference)
//
#include <hip/hip_runtime.h>

// GCN 2-layer forward, atomic-free aggregation via on-device CSR.
// x:[N,128] f32, edge_index:[2,E] int32, W1:[128,64], b1:[64], W2:[64,64], b2:[64]
//
// CSR build lessons:
//  r2:  per-element f32 atomics on agg -> 1.8GB L2 RMW traffic (90% of runtime).
//  r7:  per-node scatter cursors -> 13x write amp (12.5K open frontiers/XCD).
//  r8:  nt-load hints don't fix frontier eviction.
//  r11: 196 shared atomic cursors -> serialization + cross-XCD false sharing.
//  r12: deterministic 3-pass radix binning fixed the build.
//  r13: k_agg FETCH=189MB = 8 XCD x 25.6MB table = compulsory floor for a
//       random graph with private L2s. 59us @ 3.2TB/s fill, VALU 15%, occ 69%
//       -> still latency-bound. This round: 8 independent gathers in flight
//       (8KB/wave). If no gain, 3.2TB/s IS the random-64B L3->L2 roofline.

#define FILL_CS 8192
#define BSH 9                   // 512 nodes per bucket

// P1: per-chunk histogram (LDS atomics only).
__global__ __launch_bounds__(256) void k_hist(const int* __restrict__ dst,
                                              int* __restrict__ hist,
                                              int E, int nbkt) {
  __shared__ int lc[256];
  int c = blockIdx.x;
  lc[threadIdx.x] = 0;
  __syncthreads();
  int base = c * FILL_CS;
  int end = base + FILL_CS;
  if (end > E) end = E;
  for (int e = base + threadIdx.x; e < end; e += 256)
    atomicAdd(&lc[dst[e] >> BSH], 1);
  __syncthreads();
  if (threadIdx.x < nbkt) hist[c * nbkt + threadIdx.x] = lc[threadIdx.x];
}

// P2a: one block per bucket; exclusive scan of hist[.][b] over chunks.
__global__ __launch_bounds__(256) void k_choff(const int* __restrict__ hist,
                                               int* __restrict__ choff,
                                               int* __restrict__ total,
                                               int nchunk, int nbkt) {
  __shared__ int tmp[256];
  int b = blockIdx.x;
  int c = threadIdx.x;
  int v = (c < nchunk) ? hist[c * nbkt + b] : 0;
  tmp[c] = v;
  __syncthreads();
  for (int off = 1; off < 256; off <<= 1) {
    int t = (c >= off) ? tmp[c - off] : 0;
    __syncthreads();
    tmp[c] += t;
    __syncthreads();
  }
  if (c < nchunk) choff[c * nbkt + b] = tmp[c] - v;  // exclusive
  if (c == 255) total[b] = tmp[255];
}

// P2b: single block; exclusive scan of total -> bbase; bbase[nbkt]=E.
__global__ __launch_bounds__(256) void k_bbase(const int* __restrict__ total,
                                               int* __restrict__ bbase,
                                               int nbkt, int E) {
  __shared__ int tmp[256];
  int i = threadIdx.x;
  int v = (i < nbkt) ? total[i] : 0;
  tmp[i] = v;
  __syncthreads();
  for (int off = 1; off < 256; off <<= 1) {
    int t = (i >= off) ? tmp[i - off] : 0;
    __syncthreads();
    tmp[i] += t;
    __syncthreads();
  }
  if (i < nbkt) bbase[i] = tmp[i] - v;
  if (i == 0) bbase[nbkt] = E;
}

// P3: deterministic bucket scatter; only LDS atomics.
__global__ __launch_bounds__(256) void k_fill3(const int* __restrict__ src,
                                               const int* __restrict__ dst,
                                               const int* __restrict__ choff,
                                               const int* __restrict__ bbase,
                                               unsigned int* __restrict__ bkt,
                                               int E, int nbkt) {
  __shared__ int cur[256];
  int c = blockIdx.x;
  if (threadIdx.x < nbkt)
    cur[threadIdx.x] = bbase[threadIdx.x] + choff[c * nbkt + threadIdx.x];
  __syncthreads();
  int base = c * FILL_CS;
  int end = base + FILL_CS;
  if (end > E) end = E;
  for (int e = base + threadIdx.x; e < end; e += 256) {
    int d = dst[e];
    int s = src[e];
    int p = atomicAdd(&cur[d >> BSH], 1);
    bkt[p] = ((unsigned int)(d & 511) << 17) | (unsigned int)s;
  }
}

// Per-bucket LDS histogram -> cnt + dinv (fused; covers every node, no memset).
__global__ __launch_bounds__(256) void k_bcount(const unsigned int* __restrict__ bkt,
                                                const int* __restrict__ bbase,
                                                int* __restrict__ cnt,
                                                float* __restrict__ dinv, int N) {
  __shared__ int lc[512];
  int b = blockIdx.x;
  lc[threadIdx.x] = 0;
  lc[threadIdx.x + 256] = 0;
  __syncthreads();
  int beg = bbase[b], end = bbase[b + 1];
  for (int i = beg + threadIdx.x; i < end; i += 256)
    atomicAdd(&lc[bkt[i] >> 17], 1);
  __syncthreads();
  int base = b << BSH;
#pragma unroll
  for (int k = 0; k < 2; ++k) {
    int i = threadIdx.x + k * 256;
    if (base + i < N) {
      int cv = lc[i];
      cnt[base + i] = cv;
      dinv[base + i] = rsqrtf((float)cv + 1.0f);  // self-loop adds 1
    }
  }
}

// ---- 3-kernel exclusive scan of cnt[N] -> row[N], block sums in bsum ----
__global__ __launch_bounds__(256) void k_scan1(const int* __restrict__ cnt,
                                               int* __restrict__ row,
                                               int* __restrict__ bsum, int N) {
  __shared__ int tmp[256];
  int i = blockIdx.x * 256 + threadIdx.x;
  int v = (i < N) ? cnt[i] : 0;
  tmp[threadIdx.x] = v;
  __syncthreads();
  for (int off = 1; off < 256; off <<= 1) {
    int t = (threadIdx.x >= off) ? tmp[threadIdx.x - off] : 0;
    __syncthreads();
    tmp[threadIdx.x] += t;
    __syncthreads();
  }
  if (i < N) row[i] = tmp[threadIdx.x] - v;  // exclusive
  if (threadIdx.x == 255) bsum[blockIdx.x] = tmp[255];
}

__global__ __launch_bounds__(512) void k_scan2(int* __restrict__ bsum, int nb) {
  __shared__ int tmp[512];
  int v = (threadIdx.x < nb) ? bsum[threadIdx.x] : 0;
  tmp[threadIdx.x] = v;
  __syncthreads();
  for (int off = 1; off < 512; off <<= 1) {
    int t = (threadIdx.x >= off) ? tmp[threadIdx.x - off] : 0;
    __syncthreads();
    tmp[threadIdx.x] += t;
    __syncthreads();
  }
  if (threadIdx.x < nb) bsum[threadIdx.x] = tmp[threadIdx.x] - v;  // exclusive
}

__global__ __launch_bounds__(256) void k_scan3(int* __restrict__ row,
                                               const int* __restrict__ bsum,
                                               int N, int E) {
  int i = blockIdx.x * 256 + threadIdx.x;
  if (i < N) row[i] += bsum[blockIdx.x];
  if (i == 0) row[N] = E;
}

// Per-bucket fine fill: LDS cursors; eidx writes confined to the bucket's
// contiguous row-range (single block, single XCD, written once).
__global__ __launch_bounds__(256) void k_bfill(const unsigned int* __restrict__ bkt,
                                               const int* __restrict__ bbase,
                                               const int* __restrict__ row,
                                               int* __restrict__ eidx, int N) {
  __shared__ int fl[512];
  int b = blockIdx.x;
  fl[threadIdx.x] = 0;
  fl[threadIdx.x + 256] = 0;
  __syncthreads();
  int beg = bbase[b], end = bbase[b + 1];
  int base = b << BSH;
  for (int i = beg + threadIdx.x; i < end; i += 256) {
    unsigned int v = bkt[i];
    int dl = v >> 17;
    int s = v & 0x1FFFF;
    int ofs = atomicAdd(&fl[dl], 1);
    eidx[row[base + dl] + ofs] = s;
  }
}

// LDS-tiled GEMM: HS[node,j] = dinv[node] * sum_k X[node,k]*W[k,j].
// Block = 256 threads, tile = 64 nodes x 64 cols x full K in LDS.
// Each thread owns a 4x4 register tile (acc stays in VGPRs).
// History: acc[64]/thread -> scratch spill (VALUBusy 11%); per-lane VMEM W
// loads -> VMEM-issue bound (VALUBusy 5%). LDS staging fixes both.
template <int K>
__global__ __launch_bounds__(256) void k_gemm(const float* __restrict__ X,
                                              const float* __restrict__ W,
                                              const float* __restrict__ dinv,
                                              float* __restrict__ HS, int N) {
  __shared__ float Xs[64][K + 4];
  __shared__ float Ws[K][64];
  const int t = threadIdx.x;
  const int base = blockIdx.x * 64;

  for (int idx = t * 4; idx < 64 * K; idx += 1024) {
    int r = idx / K, c = idx % K;
    float4 v = make_float4(0.f, 0.f, 0.f, 0.f);
    if (base + r < N)
      v = *reinterpret_cast<const float4*>(X + (size_t)(base + r) * K + c);
    *reinterpret_cast<float4*>(&Xs[r][c]) = v;
  }
  for (int idx = t * 4; idx < K * 64; idx += 1024) {
    float4 v = *reinterpret_cast<const float4*>(W + idx);
    *reinterpret_cast<float4*>(&Ws[0][0] + idx) = v;
  }
  __syncthreads();

  const int n0 = (t >> 4) * 4;
  const int j0 = (t & 15) * 4;
  float acc[4][4];
#pragma unroll
  for (int i = 0; i < 4; ++i)
#pragma unroll
    for (int j = 0; j < 4; ++j) acc[i][j] = 0.f;

  for (int k0 = 0; k0 < K; k0 += 4) {
    float4 xv[4];
#pragma unroll
    for (int i = 0; i < 4; ++i)
      xv[i] = *reinterpret_cast<const float4*>(&Xs[n0 + i][k0]);
#pragma unroll
    for (int kk = 0; kk < 4; ++kk) {
      float4 wv = *reinterpret_cast<const float4*>(&Ws[k0 + kk][j0]);
#pragma unroll
      for (int i = 0; i < 4; ++i) {
        float xs = (kk == 0) ? xv[i].x : (kk == 1) ? xv[i].y
                 : (kk == 2) ? xv[i].z : xv[i].w;
        acc[i][0] = fmaf(xs, wv.x, acc[i][0]);
        acc[i][1] = fmaf(xs, wv.y, acc[i][1]);
        acc[i][2] = fmaf(xs, wv.z, acc[i][2]);
        acc[i][3] = fmaf(xs, wv.w, acc[i][3]);
      }
    }
  }

#pragma unroll
  for (int i = 0; i < 4; ++i) {
    int node = base + n0 + i;
    if (node < N) {
      float di = dinv[node];
      float4 o;
      o.x = acc[i][0] * di; o.y = acc[i][1] * di;
      o.z = acc[i][2] * di; o.w = acc[i][3] * di;
      *reinterpret_cast<float4*>(HS + (size_t)node * 64 + j0) = o;
    }
  }
}

// Aggregation: 16 threads per node, lane owns a float4 feature slice.
// 8-way edge unroll -> 8 independent float4 gathers in flight per lane
// (8KB/wave; the 4-way version ran 59us @ 3.2TB/s fill, latency-limited).
// hs rows are pre-scaled by dinv[src]:
// out[d] = dinv[d]*(sum_{s in in(d)} hs[s] + hs[d]) + bias   (+relu)
__global__ __launch_bounds__(256) void k_agg(const float* __restrict__ hs,
                                             const int* __restrict__ row,
                                             const int* __restrict__ eidx,
                                             const float* __restrict__ dinv,
                                             const float* __restrict__ bias,
                                             float* __restrict__ out, int N,
                                             int relu) {
  int gid = blockIdx.x * 256 + threadIdx.x;
  int node = gid >> 4;
  if (node >= N) return;
  int q = (gid & 15) * 4;
  int beg = row[node], end = row[node + 1];
  float4 a0 = make_float4(0.f, 0.f, 0.f, 0.f);
  float4 a1 = make_float4(0.f, 0.f, 0.f, 0.f);
  float4 a2 = make_float4(0.f, 0.f, 0.f, 0.f);
  float4 a3 = make_float4(0.f, 0.f, 0.f, 0.f);
  float4 a4 = make_float4(0.f, 0.f, 0.f, 0.f);
  float4 a5 = make_float4(0.f, 0.f, 0.f, 0.f);
  float4 a6 = make_float4(0.f, 0.f, 0.f, 0.f);
  float4 a7 = make_float4(0.f, 0.f, 0.f, 0.f);
  int e = beg;
  for (; e + 7 < end; e += 8) {
    int s0 = eidx[e],     s1 = eidx[e + 1], s2 = eidx[e + 2], s3 = eidx[e + 3];
    int s4 = eidx[e + 4], s5 = eidx[e + 5], s6 = eidx[e + 6], s7 = eidx[e + 7];
    float4 v0 = *reinterpret_cast<const float4*>(hs + (size_t)s0 * 64 + q);
    float4 v1 = *reinterpret_cast<const float4*>(hs + (size_t)s1 * 64 + q);
    float4 v2 = *reinterpret_cast<const float4*>(hs + (size_t)s2 * 64 + q);
    float4 v3 = *reinterpret_cast<const float4*>(hs + (size_t)s3 * 64 + q);
    float4 v4 = *reinterpret_cast<const float4*>(hs + (size_t)s4 * 64 + q);
    float4 v5 = *reinterpret_cast<const float4*>(hs + (size_t)s5 * 64 + q);
    float4 v6 = *reinterpret_cast<const float4*>(hs + (size_t)s6 * 64 + q);
    float4 v7 = *reinterpret_cast<const float4*>(hs + (size_t)s7 * 64 + q);
    a0.x += v0.x; a0.y += v0.y; a0.z += v0.z; a0.w += v0.w;
    a1.x += v1.x; a1.y += v1.y; a1.z += v1.z; a1.w += v1.w;
    a2.x += v2.x; a2.y += v2.y; a2.z += v2.z; a2.w += v2.w;
    a3.x += v3.x; a3.y += v3.y; a3.z += v3.z; a3.w += v3.w;
    a4.x += v4.x; a4.y += v4.y; a4.z += v4.z; a4.w += v4.w;
    a5.x += v5.x; a5.y += v5.y; a5.z += v5.z; a5.w += v5.w;
    a6.x += v6.x; a6.y += v6.y; a6.z += v6.z; a6.w += v6.w;
    a7.x += v7.x; a7.y += v7.y; a7.z += v7.z; a7.w += v7.w;
  }
  for (; e + 3 < end; e += 4) {
    int s0 = eidx[e], s1 = eidx[e + 1], s2 = eidx[e + 2], s3 = eidx[e + 3];
    float4 v0 = *reinterpret_cast<const float4*>(hs + (size_t)s0 * 64 + q);
    float4 v1 = *reinterpret_cast<const float4*>(hs + (size_t)s1 * 64 + q);
    float4 v2 = *reinterpret_cast<const float4*>(hs + (size_t)s2 * 64 + q);
    float4 v3 = *reinterpret_cast<const float4*>(hs + (size_t)s3 * 64 + q);
    a0.x += v0.x; a0.y += v0.y; a0.z += v0.z; a0.w += v0.w;
    a1.x += v1.x; a1.y += v1.y; a1.z += v1.z; a1.w += v1.w;
    a2.x += v2.x; a2.y += v2.y; a2.z += v2.z; a2.w += v2.w;
    a3.x += v3.x; a3.y += v3.y; a3.z += v3.z; a3.w += v3.w;
  }
  for (; e < end; ++e) {
    int s = eidx[e];
    float4 v = *reinterpret_cast<const float4*>(hs + (size_t)s * 64 + q);
    a0.x += v.x; a0.y += v.y; a0.z += v.z; a0.w += v.w;
  }
  float4 self = *reinterpret_cast<const float4*>(hs + (size_t)node * 64 + q);
  float4 bv = *reinterpret_cast<const float4*>(bias + q);
  float dd = dinv[node];
  float4 r;
  r.x = dd * (((a0.x + a1.x) + (a2.x + a3.x)) + ((a4.x + a5.x) + (a6.x + a7.x)) + self.x) + bv.x;
  r.y = dd * (((a0.y + a1.y) + (a2.y + a3.y)) + ((a4.y + a5.y) + (a6.y + a7.y)) + self.y) + bv.y;
  r.z = dd * (((a0.z + a1.z) + (a2.z + a3.z)) + ((a4.z + a5.z) + (a6.z + a7.z)) + self.z) + bv.z;
  r.w = dd * (((a0.w + a1.w) + (a2.w + a3.w)) + ((a4.w + a5.w) + (a6.w + a7.w)) + self.w) + bv.w;
  if (relu) {
    r.x = fmaxf(r.x, 0.f); r.y = fmaxf(r.y, 0.f);
    r.z = fmaxf(r.z, 0.f); r.w = fmaxf(r.w, 0.f);
  }
  *reinterpret_cast<float4*>(out + (size_t)node * 64 + q) = r;
}

extern "C" void kernel_launch(void* const* d_in, const int* in_sizes, int n_in,
                              void* d_out, int out_size, void* d_ws, size_t ws_size,
                              hipStream_t stream) {
  const float* x  = (const float*)d_in[0];
  const int*   ei = (const int*)d_in[1];
  const float* W1 = (const float*)d_in[2];
  const float* b1 = (const float*)d_in[3];
  const float* W2 = (const float*)d_in[4];
  const float* b2 = (const float*)d_in[5];
  float* out = (float*)d_out;

  const int N = in_sizes[0] / 128;  // 100000
  const int E = in_sizes[1] / 2;    // 1600000
  const int* src = ei;
  const int* dstv = ei + E;

  const int nbkt = (N + (1 << BSH) - 1) >> BSH;        // 196
  const int nchunk = (E + FILL_CS - 1) / FILL_CS;      // 196

  // workspace layout (4B units), ~40 MB total
  int*   cnt   = (int*)d_ws;                  // [N]
  int*   row   = cnt + 102400;                // [N+1]
  float* dinv  = (float*)(cnt + 205056);      // [N]
  int*   bsum  = cnt + 307456;                // [512]
  int*   hist  = cnt + 307968;                // [nchunk*nbkt]
  int*   choff = cnt + 346624;                // [nchunk*nbkt]
  int*   total = cnt + 385280;                // [nbkt]
  int*   bbase = cnt + 385536;                // [nbkt+1]
  unsigned int* bkt = (unsigned int*)(cnt + 385792);  // [E]
  int*   eidx  = cnt + 1985792;               // [E]
  float* bufA  = (float*)(cnt + 3585792);     // [N*64], 16B-aligned

  const int nb = (N + 255) / 256;
  const int ngemm = (N + 63) / 64;
  const int nagg = (N * 16 + 255) / 256;

  // ---- CSR build (deterministic, no global atomics) ----
  k_hist<<<nchunk, 256, 0, stream>>>(dstv, hist, E, nbkt);
  k_choff<<<nbkt, 256, 0, stream>>>(hist, choff, total, nchunk, nbkt);
  k_bbase<<<1, 256, 0, stream>>>(total, bbase, nbkt, E);
  k_fill3<<<nchunk, 256, 0, stream>>>(src, dstv, choff, bbase, bkt, E, nbkt);
  k_bcount<<<nbkt, 256, 0, stream>>>(bkt, bbase, cnt, dinv, N);
  k_scan1<<<nb, 256, 0, stream>>>(cnt, row, bsum, N);
  k_scan2<<<1, 512, 0, stream>>>(bsum, nb);
  k_scan3<<<nb, 256, 0, stream>>>(row, bsum, N, E);
  k_bfill<<<nbkt, 256, 0, stream>>>(bkt, bbase, row, eidx, N);

  // ---- conv1: hs1 = dinv*(x@W1) -> agg -> relu -> d_out ----
  k_gemm<128><<<ngemm, 256, 0, stream>>>(x, W1, dinv, bufA, N);
  k_agg<<<nagg, 256, 0, stream>>>(bufA, row, eidx, dinv, b1, out, N, 1);

  // ---- conv2: hs2 = dinv*(out@W2) -> agg -> d_out ----
  k_gemm<64><<<ngemm, 256, 0, stream>>>(out, W2, dinv, bufA, N);
  k_agg<<<nagg, 256, 0, stream>>>(bufA, row, eidx, dinv, b2, out, N, 0);
}

// Round 17
// 350.695 us; speedup vs baseline: 1.0304x; 1.0304x over previous
//
#include <hip/hip_runtime.h>

// GCN 2-layer forward, atomic-free aggregation via on-device CSR.
// x:[N,128] f32, edge_index:[2,E] int32, W1:[128,64], b1:[64], W2:[64,64], b2:[64]
//
// Lessons:
//  r2:  per-element f32 atomics on agg -> 1.8GB L2 RMW traffic.
//  r7:  per-node scatter cursors -> 13x write amp (12.5K open frontiers/XCD).
//  r11: 196 shared global cursors -> atomic serialization, 2168us.
//  r12: deterministic 3-pass radix binning fixed the build.
//  r13/r16: k_agg 4-way=59us, 8-way=61us, both ~3.2TB/s fill, FETCH pinned at
//       190MB (=8 XCD x table) -> random-row L2-miss service roofline; k_agg
//       is DONE (keep 4-way: VGPR 24, occ 69%).
//  r16: row[] of bucket b = bbase[b] + local scan of bucket histogram ->
//       fuse bcount+scan1/2/3+bfill into ONE kernel (k_bmake).

#define FILL_CS 8192
#define BSH 9                   // 512 nodes per bucket

// P1: per-chunk histogram (LDS atomics only).
__global__ __launch_bounds__(256) void k_hist(const int* __restrict__ dst,
                                              int* __restrict__ hist,
                                              int E, int nbkt) {
  __shared__ int lc[256];
  int c = blockIdx.x;
  lc[threadIdx.x] = 0;
  __syncthreads();
  int base = c * FILL_CS;
  int end = base + FILL_CS;
  if (end > E) end = E;
  for (int e = base + threadIdx.x; e < end; e += 256)
    atomicAdd(&lc[dst[e] >> BSH], 1);
  __syncthreads();
  if (threadIdx.x < nbkt) hist[c * nbkt + threadIdx.x] = lc[threadIdx.x];
}

// P2a: one block per bucket; exclusive scan of hist[.][b] over chunks.
__global__ __launch_bounds__(256) void k_choff(const int* __restrict__ hist,
                                               int* __restrict__ choff,
                                               int* __restrict__ total,
                                               int nchunk, int nbkt) {
  __shared__ int tmp[256];
  int b = blockIdx.x;
  int c = threadIdx.x;
  int v = (c < nchunk) ? hist[c * nbkt + b] : 0;
  tmp[c] = v;
  __syncthreads();
  for (int off = 1; off < 256; off <<= 1) {
    int t = (c >= off) ? tmp[c - off] : 0;
    __syncthreads();
    tmp[c] += t;
    __syncthreads();
  }
  if (c < nchunk) choff[c * nbkt + b] = tmp[c] - v;  // exclusive
  if (c == 255) total[b] = tmp[255];
}

// P2b: single block; exclusive scan of total -> bbase; bbase[nbkt]=E.
__global__ __launch_bounds__(256) void k_bbase(const int* __restrict__ total,
                                               int* __restrict__ bbase,
                                               int nbkt, int E) {
  __shared__ int tmp[256];
  int i = threadIdx.x;
  int v = (i < nbkt) ? total[i] : 0;
  tmp[i] = v;
  __syncthreads();
  for (int off = 1; off < 256; off <<= 1) {
    int t = (i >= off) ? tmp[i - off] : 0;
    __syncthreads();
    tmp[i] += t;
    __syncthreads();
  }
  if (i < nbkt) bbase[i] = tmp[i] - v;
  if (i == 0) bbase[nbkt] = E;
}

// P3: deterministic bucket scatter; only LDS atomics.
__global__ __launch_bounds__(256) void k_fill3(const int* __restrict__ src,
                                               const int* __restrict__ dst,
                                               const int* __restrict__ choff,
                                               const int* __restrict__ bbase,
                                               unsigned int* __restrict__ bkt,
                                               int E, int nbkt) {
  __shared__ int cur[256];
  int c = blockIdx.x;
  if (threadIdx.x < nbkt)
    cur[threadIdx.x] = bbase[threadIdx.x] + choff[c * nbkt + threadIdx.x];
  __syncthreads();
  int base = c * FILL_CS;
  int end = base + FILL_CS;
  if (end > E) end = E;
  for (int e = base + threadIdx.x; e < end; e += 256) {
    int d = dst[e];
    int s = src[e];
    int p = atomicAdd(&cur[d >> BSH], 1);
    bkt[p] = ((unsigned int)(d & 511) << 17) | (unsigned int)s;
  }
}

// P4 (fused): per-bucket histogram -> LDS 512-scan -> row+dinv -> eidx fill.
// row[] of bucket b is bbase[b] + local exclusive scan; second bkt pass hits
// L2 (32KB/bucket just read). Replaces bcount + scan1/2/3 + bfill.
__global__ __launch_bounds__(256) void k_bmake(const unsigned int* __restrict__ bkt,
                                               const int* __restrict__ bbase,
                                               int* __restrict__ row,
                                               int* __restrict__ eidx,
                                               float* __restrict__ dinv,
                                               int N, int nbkt) {
  __shared__ int lc[512];   // histogram (original counts)
  __shared__ int sc[512];   // inclusive scan -> then fill cursors
  int b = blockIdx.x;
  int t = threadIdx.x;
  lc[t] = 0; lc[t + 256] = 0;
  __syncthreads();
  int beg = bbase[b], end = bbase[b + 1];
  for (int i = beg + t; i < end; i += 256)
    atomicAdd(&lc[bkt[i] >> 17], 1);
  __syncthreads();
  sc[t] = lc[t]; sc[t + 256] = lc[t + 256];
  __syncthreads();
  // inclusive Hillis-Steele over 512 elems, 2 per thread
  for (int off = 1; off < 512; off <<= 1) {
    int v0 = (t >= off) ? sc[t - off] : 0;
    int v1 = (t + 256 >= off) ? sc[t + 256 - off] : 0;
    __syncthreads();
    sc[t] += v0;
    sc[t + 256] += v1;
    __syncthreads();
  }
  int base = b << BSH;
#pragma unroll
  for (int k = 0; k < 2; ++k) {
    int i = t + k * 256;
    int node = base + i;
    if (node < N) {
      int excl = sc[i] - lc[i];
      row[node] = beg + excl;
      dinv[node] = rsqrtf((float)lc[i] + 1.0f);  // self-loop adds 1
    }
  }
  if (b == nbkt - 1 && t == 0) row[N] = end;  // = E
  __syncthreads();
  // cursors = global eidx position per local node
#pragma unroll
  for (int k = 0; k < 2; ++k) {
    int i = t + k * 256;
    sc[i] = beg + (sc[i] - lc[i]);
  }
  __syncthreads();
  for (int i = beg + t; i < end; i += 256) {
    unsigned int v = bkt[i];
    int dl = v >> 17;
    int s = v & 0x1FFFF;
    int ofs = atomicAdd(&sc[dl], 1);
    eidx[ofs] = s;
  }
}

// LDS-tiled GEMM: HS[node,j] = dinv[node] * sum_k X[node,k]*W[k,j].
// Block = 256 threads, tile = 64 nodes x 64 cols x full K in LDS.
// Each thread owns a 4x4 register tile (acc stays in VGPRs).
// History: acc[64]/thread -> scratch spill (VALUBusy 11%); per-lane VMEM W
// loads -> VMEM-issue bound (VALUBusy 5%). LDS staging fixes both.
template <int K>
__global__ __launch_bounds__(256) void k_gemm(const float* __restrict__ X,
                                              const float* __restrict__ W,
                                              const float* __restrict__ dinv,
                                              float* __restrict__ HS, int N) {
  __shared__ float Xs[64][K + 4];
  __shared__ float Ws[K][64];
  const int t = threadIdx.x;
  const int base = blockIdx.x * 64;

  for (int idx = t * 4; idx < 64 * K; idx += 1024) {
    int r = idx / K, c = idx % K;
    float4 v = make_float4(0.f, 0.f, 0.f, 0.f);
    if (base + r < N)
      v = *reinterpret_cast<const float4*>(X + (size_t)(base + r) * K + c);
    *reinterpret_cast<float4*>(&Xs[r][c]) = v;
  }
  for (int idx = t * 4; idx < K * 64; idx += 1024) {
    float4 v = *reinterpret_cast<const float4*>(W + idx);
    *reinterpret_cast<float4*>(&Ws[0][0] + idx) = v;
  }
  __syncthreads();

  const int n0 = (t >> 4) * 4;
  const int j0 = (t & 15) * 4;
  float acc[4][4];
#pragma unroll
  for (int i = 0; i < 4; ++i)
#pragma unroll
    for (int j = 0; j < 4; ++j) acc[i][j] = 0.f;

  for (int k0 = 0; k0 < K; k0 += 4) {
    float4 xv[4];
#pragma unroll
    for (int i = 0; i < 4; ++i)
      xv[i] = *reinterpret_cast<const float4*>(&Xs[n0 + i][k0]);
#pragma unroll
    for (int kk = 0; kk < 4; ++kk) {
      float4 wv = *reinterpret_cast<const float4*>(&Ws[k0 + kk][j0]);
#pragma unroll
      for (int i = 0; i < 4; ++i) {
        float xs = (kk == 0) ? xv[i].x : (kk == 1) ? xv[i].y
                 : (kk == 2) ? xv[i].z : xv[i].w;
        acc[i][0] = fmaf(xs, wv.x, acc[i][0]);
        acc[i][1] = fmaf(xs, wv.y, acc[i][1]);
        acc[i][2] = fmaf(xs, wv.z, acc[i][2]);
        acc[i][3] = fmaf(xs, wv.w, acc[i][3]);
      }
    }
  }

#pragma unroll
  for (int i = 0; i < 4; ++i) {
    int node = base + n0 + i;
    if (node < N) {
      float di = dinv[node];
      float4 o;
      o.x = acc[i][0] * di; o.y = acc[i][1] * di;
      o.z = acc[i][2] * di; o.w = acc[i][3] * di;
      *reinterpret_cast<float4*>(HS + (size_t)node * 64 + j0) = o;
    }
  }
}

// Aggregation: 16 threads per node, lane owns a float4 feature slice, 4-way
// edge unroll (r16: 4-way=59us beats 8-way=61us; at the ~3.2TB/s random-row
// L2-miss service roofline, FETCH=190MB compulsory). hs pre-scaled by dinv:
// out[d] = dinv[d]*(sum_{s in in(d)} hs[s] + hs[d]) + bias   (+relu)
__global__ __launch_bounds__(256) void k_agg(const float* __restrict__ hs,
                                             const int* __restrict__ row,
                                             const int* __restrict__ eidx,
                                             const float* __restrict__ dinv,
                                             const float* __restrict__ bias,
                                             float* __restrict__ out, int N,
                                             int relu) {
  int gid = blockIdx.x * 256 + threadIdx.x;
  int node = gid >> 4;
  if (node >= N) return;
  int q = (gid & 15) * 4;
  int beg = row[node], end = row[node + 1];
  float4 a0 = make_float4(0.f, 0.f, 0.f, 0.f);
  float4 a1 = make_float4(0.f, 0.f, 0.f, 0.f);
  float4 a2 = make_float4(0.f, 0.f, 0.f, 0.f);
  float4 a3 = make_float4(0.f, 0.f, 0.f, 0.f);
  int e = beg;
  for (; e + 3 < end; e += 4) {
    int s0 = eidx[e], s1 = eidx[e + 1], s2 = eidx[e + 2], s3 = eidx[e + 3];
    float4 v0 = *reinterpret_cast<const float4*>(hs + (size_t)s0 * 64 + q);
    float4 v1 = *reinterpret_cast<const float4*>(hs + (size_t)s1 * 64 + q);
    float4 v2 = *reinterpret_cast<const float4*>(hs + (size_t)s2 * 64 + q);
    float4 v3 = *reinterpret_cast<const float4*>(hs + (size_t)s3 * 64 + q);
    a0.x += v0.x; a0.y += v0.y; a0.z += v0.z; a0.w += v0.w;
    a1.x += v1.x; a1.y += v1.y; a1.z += v1.z; a1.w += v1.w;
    a2.x += v2.x; a2.y += v2.y; a2.z += v2.z; a2.w += v2.w;
    a3.x += v3.x; a3.y += v3.y; a3.z += v3.z; a3.w += v3.w;
  }
  for (; e < end; ++e) {
    int s = eidx[e];
    float4 v = *reinterpret_cast<const float4*>(hs + (size_t)s * 64 + q);
    a0.x += v.x; a0.y += v.y; a0.z += v.z; a0.w += v.w;
  }
  float4 self = *reinterpret_cast<const float4*>(hs + (size_t)node * 64 + q);
  float4 bv = *reinterpret_cast<const float4*>(bias + q);
  float dd = dinv[node];
  float4 r;
  r.x = dd * ((a0.x + a1.x) + (a2.x + a3.x) + self.x) + bv.x;
  r.y = dd * ((a0.y + a1.y) + (a2.y + a3.y) + self.y) + bv.y;
  r.z = dd * ((a0.z + a1.z) + (a2.z + a3.z) + self.z) + bv.z;
  r.w = dd * ((a0.w + a1.w) + (a2.w + a3.w) + self.w) + bv.w;
  if (relu) {
    r.x = fmaxf(r.x, 0.f); r.y = fmaxf(r.y, 0.f);
    r.z = fmaxf(r.z, 0.f); r.w = fmaxf(r.w, 0.f);
  }
  *reinterpret_cast<float4*>(out + (size_t)node * 64 + q) = r;
}

extern "C" void kernel_launch(void* const* d_in, const int* in_sizes, int n_in,
                              void* d_out, int out_size, void* d_ws, size_t ws_size,
                              hipStream_t stream) {
  const float* x  = (const float*)d_in[0];
  const int*   ei = (const int*)d_in[1];
  const float* W1 = (const float*)d_in[2];
  const float* b1 = (const float*)d_in[3];
  const float* W2 = (const float*)d_in[4];
  const float* b2 = (const float*)d_in[5];
  float* out = (float*)d_out;

  const int N = in_sizes[0] / 128;  // 100000
  const int E = in_sizes[1] / 2;    // 1600000
  const int* src = ei;
  const int* dstv = ei + E;

  const int nbkt = (N + (1 << BSH) - 1) >> BSH;        // 196
  const int nchunk = (E + FILL_CS - 1) / FILL_CS;      // 196

  // workspace layout (4B units), ~39.5 MB total
  int*   row   = (int*)d_ws;                  // [N+1]
  float* dinv  = (float*)((int*)d_ws + 102400);       // [N]
  int*   hist  = (int*)d_ws + 204800;         // [nchunk*nbkt]
  int*   choff = (int*)d_ws + 243216;         // [nchunk*nbkt]
  int*   total = (int*)d_ws + 281632;         // [nbkt]
  int*   bbase = (int*)d_ws + 281856;         // [nbkt+1]
  unsigned int* bkt = (unsigned int*)((int*)d_ws + 282112);  // [E]
  int*   eidx  = (int*)d_ws + 1882112;        // [E]
  float* bufA  = (float*)((int*)d_ws + 3482112);      // [N*64], 16B-aligned

  const int ngemm = (N + 63) / 64;
  const int nagg = (N * 16 + 255) / 256;

  // ---- CSR build (deterministic, no global atomics) ----
  k_hist<<<nchunk, 256, 0, stream>>>(dstv, hist, E, nbkt);
  k_choff<<<nbkt, 256, 0, stream>>>(hist, choff, total, nchunk, nbkt);
  k_bbase<<<1, 256, 0, stream>>>(total, bbase, nbkt, E);
  k_fill3<<<nchunk, 256, 0, stream>>>(src, dstv, choff, bbase, bkt, E, nbkt);
  k_bmake<<<nbkt, 256, 0, stream>>>(bkt, bbase, row, eidx, dinv, N, nbkt);

  // ---- conv1: hs1 = dinv*(x@W1) -> agg -> relu -> d_out ----
  k_gemm<128><<<ngemm, 256, 0, stream>>>(x, W1, dinv, bufA, N);
  k_agg<<<nagg, 256, 0, stream>>>(bufA, row, eidx, dinv, b1, out, N, 1);

  // ---- conv2: hs2 = dinv*(out@W2) -> agg -> d_out ----
  k_gemm<64><<<ngemm, 256, 0, stream>>>(out, W2, dinv, bufA, N);
  k_agg<<<nagg, 256, 0, stream>>>(bufA, row, eidx, dinv, b2, out, N, 0);
}